// Round 4
// baseline (648.685 us; speedup 1.0000x reference)
//
#include <hip/hip_runtime.h>
#include <hip/hip_bf16.h>

typedef __bf16 bf16_t;
typedef __bf16 bf16x2 __attribute__((ext_vector_type(2)));
typedef __bf16 bf16x4 __attribute__((ext_vector_type(4)));
typedef __bf16 bf16x8 __attribute__((ext_vector_type(8)));
typedef float f32x4 __attribute__((ext_vector_type(4)));
typedef float f32x16 __attribute__((ext_vector_type(16)));
typedef unsigned int u32x4 __attribute__((ext_vector_type(4)));

#define SCALE 0.08838834764831845f
#define NEG_MASK -1e10f      // matches reference; exp underflows to exact 0
#define NEG_INIT -3e38f      // running-max init; finite so no inf-inf paths
#define DEFER_THR 8.0f       // T13: tolerate m staleness up to e^8 in P

constexpr int H_ = 16;
constexpr int KH_ = 4;
constexpr int D_ = 128;
constexpr int BM = 128;  // q rows per workgroup (4 waves x 32 rows)
constexpr int BN = 64;   // keys per tile

constexpr int K_STRIDE = 136;  // K tile [64][128]+pad  (17408 B)
constexpr int V_STRIDE = 72;   // V^T tile [128][64]+pad (18432 B)
// no lds_p: P exchanged in-register via shfl_xor(32). LDS total 35840 B.

// R6: swapped-operand 16x16 MFMA; per-lane softmax. 545->402us.
// R7: T14 prefetch+setprio+defer-max: 402->392 (miss; latency wasn't it).
// R8 (this round): counters showed avg occupancy ~1 WG/CU (dispatch-order
// tail) and LDS pipe ~45% busy at n=1 (structural ceiling at n=3).
//   * 32x32x16 MFMA, BM=128: halves LDS-read + staging cost per FLOP.
//   * P C->B-layout exchange fully in-register (lane^32 swap): lds_p gone.
//   * LPT grid: longest WGs dispatched first (1-D grid, rank-major).
//   * fully-masked waves skip compute on the last diagonal tile.
__global__ __launch_bounds__(256, 3)
void fa_fwd(const float* __restrict__ qg,
            const float* __restrict__ kg,
            const float* __restrict__ vg,
            float* __restrict__ og,
            int S, int nqt, int B)
{
    // ---- LPT decode: rank-major so all biggest WGs dispatch first
    const int gid  = blockIdx.x;
    const int hbN  = H_ * B;
    const int rank = gid / hbN;          // 0 = most work
    const int hb   = gid - rank * hbN;
    const int h    = hb & (H_ - 1);
    const int b    = hb >> 4;            // H_ == 16
    const int qt   = (nqt - 1) - rank;
    const int kh   = h / (H_ / KH_);     // GQA: 4 q-heads per kv-head

    const int tid  = threadIdx.x;
    const int wid  = tid >> 6;
    const int lane = tid & 63;
    const int l32  = lane & 31;
    const int hi   = lane >> 5;          // half-group within wave

    __shared__ bf16_t lds_k[BN * K_STRIDE];
    __shared__ bf16_t lds_v[D_ * V_STRIDE];   // transposed: [d][key]

    const int  q0   = qt * BM;
    const long tok0 = (long)b * S;
    const int  qrow = q0 + wid * 32 + l32;    // the q-row this lane owns
    constexpr int KH_D = KH_ * D_;

    // ---- hoisted staging bases
    const float* kbase = kg + (((long)(tok0 + (tid >> 5))) * KH_ + kh) * D_
                            + (tid & 31) * 4;
    const float* vbase = vg + (((long)(tok0 + (tid & 63))) * KH_ + kh) * D_
                            + (tid >> 6) * 32;
    bf16_t* kw = &lds_k[(tid >> 5) * K_STRIDE + (tid & 31) * 4];
    bf16_t* vw = &lds_v[(tid >> 6) * 32 * V_STRIDE + (tid & 63)];

    // ---- Q fragments (B-layout, 32x32x16: lane holds Q[q=l32][dk*16+8*hi+j])
    bf16x8 qfrag[8];
    {
        const float* qp = qg + ((tok0 + qrow) * H_ + h) * D_;
        #pragma unroll
        for (int dk = 0; dk < 8; ++dk) {
            f32x4 a = *reinterpret_cast<const f32x4*>(qp + dk * 16 + 8 * hi);
            f32x4 c = *reinterpret_cast<const f32x4*>(qp + dk * 16 + 8 * hi + 4);
            #pragma unroll
            for (int j = 0; j < 4; ++j) {
                qfrag[dk][j]     = (bf16_t)a[j];
                qfrag[dk][j + 4] = (bf16_t)c[j];
            }
        }
    }

    // O^T accumulators: oacc[dt] C-layout, d = dt*32 + (reg&3)+8*(reg>>2)+4*hi
    f32x16 oacc[4];
    #pragma unroll
    for (int i = 0; i < 4; ++i)
        #pragma unroll
        for (int e = 0; e < 16; ++e) oacc[i][e] = 0.f;
    float m_i = NEG_INIT, l_i = 0.f;

    const int nkt = 2 * qt + 2;          // causal: k-tiles up to the diagonal

    for (int kt = 0; kt < nkt; ++kt) {
        const int kst = kt * BN;
        __syncthreads();                  // prior iter's LDS reads done

        // ---- stage K tile [64][128] fp32 -> bf16 LDS
        {
            const float* kp = kbase + (long)kst * KH_D;
            #pragma unroll
            for (int it = 0; it < 8; ++it) {
                f32x4 t = *reinterpret_cast<const f32x4*>(kp + it * 8 * KH_D);
                bf16x4 w;
                w[0] = (bf16_t)t[0]; w[1] = (bf16_t)t[1];
                w[2] = (bf16_t)t[2]; w[3] = (bf16_t)t[3];
                *reinterpret_cast<bf16x4*>(&kw[it * 8 * K_STRIDE]) = w;
            }
        }
        // ---- stage V transposed: lds_v[d][key]
        {
            const float* vp = vbase + (long)kst * KH_D;
            #pragma unroll
            for (int it = 0; it < 8; ++it) {
                f32x4 t = *reinterpret_cast<const f32x4*>(vp + it * 4);
                #pragma unroll
                for (int j = 0; j < 4; ++j)
                    vw[(it * 4 + j) * V_STRIDE] = (bf16_t)t[j];
            }
        }
        __syncthreads();

        // fully-masked wave on the last diagonal tile: skip compute
        // (no barriers inside this region, so per-wave skip is safe)
        if (kst > q0 + wid * 32 + 31) continue;

        // ---- S^T = K Q^T  (32x32x16; per wave: 64 keys x 32 q-rows)
        f32x16 s[2];
        __builtin_amdgcn_s_setprio(1);
        #pragma unroll
        for (int kb = 0; kb < 2; ++kb) {
            f32x16 acc;
            #pragma unroll
            for (int e = 0; e < 16; ++e) acc[e] = 0.f;
            #pragma unroll
            for (int dk = 0; dk < 8; ++dk) {
                bf16x8 kf = *reinterpret_cast<const bf16x8*>(
                    &lds_k[(kb * 32 + l32) * K_STRIDE + dk * 16 + 8 * hi]);
                acc = __builtin_amdgcn_mfma_f32_32x32x16_bf16(kf, qfrag[dk], acc, 0, 0, 0);
            }
            s[kb] = acc;  // s[kb][reg]: key = kst+kb*32+(reg&3)+8*(reg>>2)+4*hi, q=l32
        }
        __builtin_amdgcn_s_setprio(0);

        // ---- mask + scale (per-lane; lane owns row qrow, 32 of 64 keys)
        const bool diagw = (kst + BN - 1 > q0 + wid * 32);
        if (diagw) {
            #pragma unroll
            for (int kb = 0; kb < 2; ++kb)
                #pragma unroll
                for (int r = 0; r < 16; ++r) {
                    const int key = kst + kb * 32 + (r & 3) + 8 * (r >> 2) + 4 * hi;
                    float x = s[kb][r] * SCALE;
                    s[kb][r] = (key > qrow) ? NEG_MASK : x;
                }
        } else {
            #pragma unroll
            for (int kb = 0; kb < 2; ++kb)
                #pragma unroll
                for (int r = 0; r < 16; ++r)
                    s[kb][r] *= SCALE;
        }

        // ---- online softmax: 32 in-reg values + 1 shfl (partner half)
        float mx = s[0][0];
        #pragma unroll
        for (int kb = 0; kb < 2; ++kb)
            #pragma unroll
            for (int r = 0; r < 16; ++r) mx = fmaxf(mx, s[kb][r]);
        mx = fmaxf(mx, __shfl_xor(mx, 32));

        if (__all(mx - m_i <= DEFER_THR)) {      // T13 defer-max
            float rs = 0.f;
            #pragma unroll
            for (int kb = 0; kb < 2; ++kb)
                #pragma unroll
                for (int r = 0; r < 16; ++r) {
                    float p = __expf(s[kb][r] - m_i);
                    s[kb][r] = p;
                    rs += p;
                }
            rs += __shfl_xor(rs, 32);
            l_i += rs;
        } else {
            const float mn    = fmaxf(m_i, mx);
            const float alpha = __expf(m_i - mn);
            float rs = 0.f;
            #pragma unroll
            for (int kb = 0; kb < 2; ++kb)
                #pragma unroll
                for (int r = 0; r < 16; ++r) {
                    float p = __expf(s[kb][r] - mn);
                    s[kb][r] = p;
                    rs += p;
                }
            rs += __shfl_xor(rs, 32);
            l_i = l_i * alpha + rs;
            m_i = mn;
            #pragma unroll
            for (int dt = 0; dt < 4; ++dt)
                #pragma unroll
                for (int e = 0; e < 16; ++e)
                    oacc[dt][e] *= alpha;
        }

        // ---- P: C-layout -> B-layout fully in-register.
        // Pu[kb][i] = keys kb*32 + 8*(i>>1) + 4*hi + 2*(i&1) + {0,1} (q=l32).
        unsigned Pu[2][8];
        #pragma unroll
        for (int kb = 0; kb < 2; ++kb)
            #pragma unroll
            for (int i = 0; i < 8; ++i) {
                bf16x2 t;
                t[0] = (bf16_t)s[kb][2 * i];
                t[1] = (bf16_t)s[kb][2 * i + 1];
                Pu[kb][i] = __builtin_bit_cast(unsigned, t);
            }
        // send the half the partner (lane^32) needs; receive ours.
        unsigned X[2][4];
        #pragma unroll
        for (int kb = 0; kb < 2; ++kb)
            #pragma unroll
            for (int j = 0; j < 4; ++j) {
                unsigned v = hi ? Pu[kb][(j >> 1) * 4 + (j & 1)]
                                : Pu[kb][(j >> 1) * 4 + 2 + (j & 1)];
                X[kb][j] = (unsigned)__shfl_xor((int)v, 32);
            }
        // assemble pf[ks]: B-layout, k = ks*16 + 8*hi + j
        bf16x8 pf[4];
        #pragma unroll
        for (int ks = 0; ks < 4; ++ks) {
            const int kb = ks >> 1, b4 = 4 * (ks & 1), x2 = 2 * (ks & 1);
            u32x4 pu;
            pu[0] = hi ? X[kb][x2 + 0] : Pu[kb][b4 + 0];
            pu[1] = hi ? X[kb][x2 + 1] : Pu[kb][b4 + 1];
            pu[2] = hi ? Pu[kb][b4 + 2] : X[kb][x2 + 0];
            pu[3] = hi ? Pu[kb][b4 + 3] : X[kb][x2 + 1];
            pf[ks] = __builtin_bit_cast(bf16x8, pu);
        }

        // ---- O^T += V^T P^T  (32x32x16)
        __builtin_amdgcn_s_setprio(1);
        #pragma unroll
        for (int dt = 0; dt < 4; ++dt)
            #pragma unroll
            for (int ks = 0; ks < 4; ++ks) {
                bf16x8 vf = *reinterpret_cast<const bf16x8*>(
                    &lds_v[(dt * 32 + l32) * V_STRIDE + ks * 16 + 8 * hi]);
                oacc[dt] = __builtin_amdgcn_mfma_f32_32x32x16_bf16(vf, pf[ks], oacc[dt], 0, 0, 0);
            }
        __builtin_amdgcn_s_setprio(0);
    }

    // ---- epilogue: O /= l, f32x4 stores; d = dt*32 + 8*g + 4*hi + {0..3}
    const float inv = 1.0f / l_i;
    float* op = og + ((tok0 + qrow) * H_ + h) * D_;
    #pragma unroll
    for (int dt = 0; dt < 4; ++dt)
        #pragma unroll
        for (int g = 0; g < 4; ++g) {
            f32x4 o;
            #pragma unroll
            for (int r = 0; r < 4; ++r) o[r] = oacc[dt][4 * g + r] * inv;
            *reinterpret_cast<f32x4*>(op + dt * 32 + 8 * g + 4 * hi) = o;
        }
}

extern "C" void kernel_launch(void* const* d_in, const int* in_sizes, int n_in,
                              void* d_out, int out_size, void* d_ws, size_t ws_size,
                              hipStream_t stream) {
    const float* q = (const float*)d_in[0];
    const float* k = (const float*)d_in[1];
    const float* v = (const float*)d_in[2];
    float* out = (float*)d_out;

    const int B = in_sizes[3] - 1;
    const int T = in_sizes[0] / (H_ * D_);
    const int S = T / B;
    const int nqt = S / BM;

    dim3 grid(nqt * H_ * B);
    fa_fwd<<<grid, 256, 0, stream>>>(q, k, v, out, S, nqt, B);
}

// Round 5
// 361.208 us; speedup vs baseline: 1.7959x; 1.7959x over previous
//
#include <hip/hip_runtime.h>
#include <hip/hip_bf16.h>

typedef __bf16 bf16_t;
typedef __bf16 bf16x2 __attribute__((ext_vector_type(2)));
typedef __bf16 bf16x4 __attribute__((ext_vector_type(4)));
typedef __bf16 bf16x8 __attribute__((ext_vector_type(8)));
typedef float f32x4 __attribute__((ext_vector_type(4)));
typedef float f32x16 __attribute__((ext_vector_type(16)));
typedef unsigned int u32x4 __attribute__((ext_vector_type(4)));

#define SCALE 0.08838834764831845f
#define NEG_MASK -1e10f      // matches reference; exp underflows to exact 0
#define NEG_INIT -3e38f      // running-max init; finite so no inf-inf paths
#define DEFER_THR 8.0f       // T13: tolerate m staleness up to e^8 in P

constexpr int H_ = 16;
constexpr int KH_ = 4;
constexpr int D_ = 128;
constexpr int BM = 128;  // q rows per workgroup (4 waves x 32 rows)
constexpr int BN = 64;   // keys per tile

constexpr int K_STRIDE = 136;  // K tile [64][128]+pad  (17408 B)
constexpr int V_STRIDE = 72;   // V^T tile [128][64]+pad (18432 B)
// no lds_p: P exchanged in-register via shfl_xor(32). LDS total 35840 B.

// R6: swapped-operand 16x16 MFMA; per-lane softmax. 545->402us.
// R7: T14 prefetch+setprio+defer-max: 402->392 (miss; latency wasn't it).
// R8: 32x32 MFMA + BM=128 + in-reg P exchange + LPT. REGRESSED 556us:
//     __launch_bounds__(256,3) capped regs at ~170 < ~200 live set ->
//     in-loop scratch spill (WRITE_SIZE 65MB->942MB, VGPR_Count 84).
//     Structure validated: bank conflicts 2.05e7 -> 0, absmax unchanged.
// R9 (this round): same structure, spill removed.
//   * __launch_bounds__(256,2): 256-reg cap, fits the live set. 2 WG/CU.
//   * PV loop ks-outer with lazy pf build: only 4 P-regs live (was 28),
//     s[] dies at pack time -> allocator slack under the cap.
__global__ __launch_bounds__(256, 2)
void fa_fwd(const float* __restrict__ qg,
            const float* __restrict__ kg,
            const float* __restrict__ vg,
            float* __restrict__ og,
            int S, int nqt, int B)
{
    // ---- LPT decode: rank-major so all biggest WGs dispatch first
    const int gid  = blockIdx.x;
    const int hbN  = H_ * B;
    const int rank = gid / hbN;          // 0 = most work
    const int hb   = gid - rank * hbN;
    const int h    = hb & (H_ - 1);
    const int b    = hb >> 4;            // H_ == 16
    const int qt   = (nqt - 1) - rank;
    const int kh   = h / (H_ / KH_);     // GQA: 4 q-heads per kv-head

    const int tid  = threadIdx.x;
    const int wid  = tid >> 6;
    const int lane = tid & 63;
    const int l32  = lane & 31;
    const int hi   = lane >> 5;          // half-group within wave

    __shared__ bf16_t lds_k[BN * K_STRIDE];
    __shared__ bf16_t lds_v[D_ * V_STRIDE];   // transposed: [d][key]

    const int  q0   = qt * BM;
    const long tok0 = (long)b * S;
    const int  qrow = q0 + wid * 32 + l32;    // the q-row this lane owns
    constexpr int KH_D = KH_ * D_;

    // ---- hoisted staging bases
    const float* kbase = kg + (((long)(tok0 + (tid >> 5))) * KH_ + kh) * D_
                            + (tid & 31) * 4;
    const float* vbase = vg + (((long)(tok0 + (tid & 63))) * KH_ + kh) * D_
                            + (tid >> 6) * 32;
    bf16_t* kw = &lds_k[(tid >> 5) * K_STRIDE + (tid & 31) * 4];
    bf16_t* vw = &lds_v[(tid >> 6) * 32 * V_STRIDE + (tid & 63)];

    // ---- Q fragments (B-layout, 32x32x16: lane holds Q[q=l32][dk*16+8*hi+j])
    bf16x8 qfrag[8];
    {
        const float* qp = qg + ((tok0 + qrow) * H_ + h) * D_;
        #pragma unroll
        for (int dk = 0; dk < 8; ++dk) {
            f32x4 a = *reinterpret_cast<const f32x4*>(qp + dk * 16 + 8 * hi);
            f32x4 c = *reinterpret_cast<const f32x4*>(qp + dk * 16 + 8 * hi + 4);
            #pragma unroll
            for (int j = 0; j < 4; ++j) {
                qfrag[dk][j]     = (bf16_t)a[j];
                qfrag[dk][j + 4] = (bf16_t)c[j];
            }
        }
    }

    // O^T accumulators: oacc[dt] C-layout, d = dt*32 + (reg&3)+8*(reg>>2)+4*hi
    f32x16 oacc[4];
    #pragma unroll
    for (int i = 0; i < 4; ++i)
        #pragma unroll
        for (int e = 0; e < 16; ++e) oacc[i][e] = 0.f;
    float m_i = NEG_INIT, l_i = 0.f;

    const int nkt = 2 * qt + 2;          // causal: k-tiles up to the diagonal

    for (int kt = 0; kt < nkt; ++kt) {
        const int kst = kt * BN;
        __syncthreads();                  // prior iter's LDS reads done

        // ---- stage K tile [64][128] fp32 -> bf16 LDS
        {
            const float* kp = kbase + (long)kst * KH_D;
            #pragma unroll
            for (int it = 0; it < 8; ++it) {
                f32x4 t = *reinterpret_cast<const f32x4*>(kp + it * 8 * KH_D);
                bf16x4 w;
                w[0] = (bf16_t)t[0]; w[1] = (bf16_t)t[1];
                w[2] = (bf16_t)t[2]; w[3] = (bf16_t)t[3];
                *reinterpret_cast<bf16x4*>(&kw[it * 8 * K_STRIDE]) = w;
            }
        }
        // ---- stage V transposed: lds_v[d][key]
        {
            const float* vp = vbase + (long)kst * KH_D;
            #pragma unroll
            for (int it = 0; it < 8; ++it) {
                f32x4 t = *reinterpret_cast<const f32x4*>(vp + it * 4);
                #pragma unroll
                for (int j = 0; j < 4; ++j)
                    vw[(it * 4 + j) * V_STRIDE] = (bf16_t)t[j];
            }
        }
        __syncthreads();

        // fully-masked wave on the last diagonal tile: skip compute
        // (no barriers inside this region, so per-wave skip is safe)
        if (kst > q0 + wid * 32 + 31) continue;

        // ---- S^T = K Q^T  (32x32x16; per wave: 64 keys x 32 q-rows)
        f32x16 s[2];
        __builtin_amdgcn_s_setprio(1);
        #pragma unroll
        for (int kb = 0; kb < 2; ++kb) {
            f32x16 acc;
            #pragma unroll
            for (int e = 0; e < 16; ++e) acc[e] = 0.f;
            #pragma unroll
            for (int dk = 0; dk < 8; ++dk) {
                bf16x8 kf = *reinterpret_cast<const bf16x8*>(
                    &lds_k[(kb * 32 + l32) * K_STRIDE + dk * 16 + 8 * hi]);
                acc = __builtin_amdgcn_mfma_f32_32x32x16_bf16(kf, qfrag[dk], acc, 0, 0, 0);
            }
            s[kb] = acc;  // s[kb][reg]: key = kst+kb*32+(reg&3)+8*(reg>>2)+4*hi, q=l32
        }
        __builtin_amdgcn_s_setprio(0);

        // ---- mask + scale (per-lane; lane owns row qrow, 32 of 64 keys)
        const bool diagw = (kst + BN - 1 > q0 + wid * 32);
        if (diagw) {
            #pragma unroll
            for (int kb = 0; kb < 2; ++kb)
                #pragma unroll
                for (int r = 0; r < 16; ++r) {
                    const int key = kst + kb * 32 + (r & 3) + 8 * (r >> 2) + 4 * hi;
                    float x = s[kb][r] * SCALE;
                    s[kb][r] = (key > qrow) ? NEG_MASK : x;
                }
        } else {
            #pragma unroll
            for (int kb = 0; kb < 2; ++kb)
                #pragma unroll
                for (int r = 0; r < 16; ++r)
                    s[kb][r] *= SCALE;
        }

        // ---- online softmax: 32 in-reg values + 1 shfl (partner half)
        float mx = s[0][0];
        #pragma unroll
        for (int kb = 0; kb < 2; ++kb)
            #pragma unroll
            for (int r = 0; r < 16; ++r) mx = fmaxf(mx, s[kb][r]);
        mx = fmaxf(mx, __shfl_xor(mx, 32));

        if (__all(mx - m_i <= DEFER_THR)) {      // T13 defer-max
            float rs = 0.f;
            #pragma unroll
            for (int kb = 0; kb < 2; ++kb)
                #pragma unroll
                for (int r = 0; r < 16; ++r) {
                    float p = __expf(s[kb][r] - m_i);
                    s[kb][r] = p;
                    rs += p;
                }
            rs += __shfl_xor(rs, 32);
            l_i += rs;
        } else {
            const float mn    = fmaxf(m_i, mx);
            const float alpha = __expf(m_i - mn);
            float rs = 0.f;
            #pragma unroll
            for (int kb = 0; kb < 2; ++kb)
                #pragma unroll
                for (int r = 0; r < 16; ++r) {
                    float p = __expf(s[kb][r] - mn);
                    s[kb][r] = p;
                    rs += p;
                }
            rs += __shfl_xor(rs, 32);
            l_i = l_i * alpha + rs;
            m_i = mn;
            #pragma unroll
            for (int dt = 0; dt < 4; ++dt)
                #pragma unroll
                for (int e = 0; e < 16; ++e)
                    oacc[dt][e] *= alpha;
        }

        // ---- P pack: C-layout pairs -> bf16x2 words; s[] dies here.
        // Pu[kb][i] = keys kb*32 + 8*(i>>1) + 4*hi + 2*(i&1) + {0,1} (q=l32).
        unsigned Pu[2][8];
        #pragma unroll
        for (int kb = 0; kb < 2; ++kb)
            #pragma unroll
            for (int i = 0; i < 8; ++i) {
                bf16x2 t;
                t[0] = (bf16_t)s[kb][2 * i];
                t[1] = (bf16_t)s[kb][2 * i + 1];
                Pu[kb][i] = __builtin_bit_cast(unsigned, t);
            }

        // ---- O^T += V^T P^T  (32x32x16), ks-outer with lazy pf build:
        // per ks: 2 shfl_xor(32) + 4 selects -> one live pf (4 regs).
        __builtin_amdgcn_s_setprio(1);
        #pragma unroll
        for (int ks = 0; ks < 4; ++ks) {
            const int kb = ks >> 1, b4 = 4 * (ks & 1);
            // hi lanes send Pu[b4+t], lo lanes send Pu[b4+2+t] (t=0,1)
            unsigned v0 = hi ? Pu[kb][b4 + 0] : Pu[kb][b4 + 2];
            unsigned v1 = hi ? Pu[kb][b4 + 1] : Pu[kb][b4 + 3];
            unsigned x0 = (unsigned)__shfl_xor((int)v0, 32);
            unsigned x1 = (unsigned)__shfl_xor((int)v1, 32);
            u32x4 pu;
            pu[0] = hi ? x0 : Pu[kb][b4 + 0];
            pu[1] = hi ? x1 : Pu[kb][b4 + 1];
            pu[2] = hi ? Pu[kb][b4 + 2] : x0;
            pu[3] = hi ? Pu[kb][b4 + 3] : x1;
            bf16x8 pf = __builtin_bit_cast(bf16x8, pu);
            #pragma unroll
            for (int dt = 0; dt < 4; ++dt) {
                bf16x8 vf = *reinterpret_cast<const bf16x8*>(
                    &lds_v[(dt * 32 + l32) * V_STRIDE + ks * 16 + 8 * hi]);
                oacc[dt] = __builtin_amdgcn_mfma_f32_32x32x16_bf16(vf, pf, oacc[dt], 0, 0, 0);
            }
        }
        __builtin_amdgcn_s_setprio(0);
    }

    // ---- epilogue: O /= l, f32x4 stores; d = dt*32 + 8*g + 4*hi + {0..3}
    const float inv = 1.0f / l_i;
    float* op = og + ((tok0 + qrow) * H_ + h) * D_;
    #pragma unroll
    for (int dt = 0; dt < 4; ++dt)
        #pragma unroll
        for (int g = 0; g < 4; ++g) {
            f32x4 o;
            #pragma unroll
            for (int r = 0; r < 4; ++r) o[r] = oacc[dt][4 * g + r] * inv;
            *reinterpret_cast<f32x4*>(op + dt * 32 + 8 * g + 4 * hi) = o;
        }
}

extern "C" void kernel_launch(void* const* d_in, const int* in_sizes, int n_in,
                              void* d_out, int out_size, void* d_ws, size_t ws_size,
                              hipStream_t stream) {
    const float* q = (const float*)d_in[0];
    const float* k = (const float*)d_in[1];
    const float* v = (const float*)d_in[2];
    float* out = (float*)d_out;

    const int B = in_sizes[3] - 1;
    const int T = in_sizes[0] / (H_ * D_);
    const int S = T / B;
    const int nqt = S / BM;

    dim3 grid(nqt * H_ * B);
    fa_fwd<<<grid, 256, 0, stream>>>(q, k, v, out, S, nqt, B);
}

// Round 7
// 353.008 us; speedup vs baseline: 1.8376x; 1.0232x over previous
//
#include <hip/hip_runtime.h>
#include <hip/hip_bf16.h>

typedef __bf16 bf16_t;
typedef __bf16 bf16x2 __attribute__((ext_vector_type(2)));
typedef __bf16 bf16x4 __attribute__((ext_vector_type(4)));
typedef __bf16 bf16x8 __attribute__((ext_vector_type(8)));
typedef float f32x4 __attribute__((ext_vector_type(4)));
typedef float f32x16 __attribute__((ext_vector_type(16)));
typedef unsigned int u32x4 __attribute__((ext_vector_type(4)));

#define SCALE 0.08838834764831845f
#define NEG_MASK -1e10f      // matches reference; exp underflows to exact 0
#define NEG_INIT -3e38f      // running-max init; finite so no inf-inf paths
#define DEFER_THR 8.0f       // T13: tolerate m staleness up to e^8 in P

constexpr int H_ = 16;
constexpr int KH_ = 4;
constexpr int D_ = 128;
constexpr int BM = 128;  // q rows per workgroup (4 waves x 32 rows)
constexpr int BN = 128;  // keys per tile (R10: was 64)

constexpr int K_STRIDE = 136;  // K tile [128][128]+pad  (34816 B)
constexpr int V_STRIDE = 136;  // V^T tile [128][128]+pad (34816 B)
// LDS total 69632 B -> 2 WGs/CU (same residency as R9's 35840).

// R6: swapped-operand 16x16 MFMA; per-lane softmax. 545->402us.
// R7: T14 prefetch+setprio+defer-max: 402->392 (miss; latency wasn't it).
// R8: 32x32 MFMA + BM=128 + in-reg P exchange + LPT; regressed on spill
//     ((256,3) cap). R9: (256,2) + lazy pf build -> 266us, no spill,
//     bank conflicts 0, MfmaUtil 10.9, Occ 22% (2 WG/CU), all pipes low.
// R10 (resubmitted; R6 bench was a broker timeout, kernel never measured):
//     still latency-bound with ~9.4k cy/iteration of which a large part is
//     per-tile FIXED cost (2 barriers, exposed staging chain, softmax fixed
//     overhead, oacc rescale).
//   * BN=128: halves iteration count -> halves all per-tile fixed costs
//     per key. LDS 69.6KB keeps 2 WGs/CU.
//   * quad-XCD swizzle: the 4 q-heads sharing (b,kh) K/V land on the SAME
//     XCD (consecutive dispatch round-robins XCDs) -> K/V L2-shared,
//     FETCH_SIZE down, staging load latency down. Bijective for nwg%32==0.
__global__ __launch_bounds__(256, 2)
void fa_fwd(const float* __restrict__ qg,
            const float* __restrict__ kg,
            const float* __restrict__ vg,
            float* __restrict__ og,
            int S, int nqt, int B)
{
    // ---- XCD swizzle (quad-grouping) + LPT decode
    const int nwg = gridDim.x;
    const int dsp = blockIdx.x;
    int gid;
    if ((nwg & 31) == 0) {
        const int xcd  = dsp & 7;
        const int slot = dsp >> 3;
        gid = 4 * (xcd + 8 * (slot >> 2)) + (slot & 3);
    } else {
        gid = dsp;
    }
    const int hbN  = H_ * B;
    const int rank = gid / hbN;          // 0 = most work (LPT)
    const int hb   = gid - rank * hbN;
    const int h    = hb & (H_ - 1);
    const int b    = hb >> 4;            // H_ == 16
    const int qt   = (nqt - 1) - rank;
    const int kh   = h / (H_ / KH_);     // GQA: 4 q-heads per kv-head

    const int tid  = threadIdx.x;
    const int wid  = tid >> 6;
    const int lane = tid & 63;
    const int l32  = lane & 31;
    const int hi   = lane >> 5;          // half-group within wave

    __shared__ bf16_t lds_k[BN * K_STRIDE];
    __shared__ bf16_t lds_v[D_ * V_STRIDE];   // transposed: [d][key]

    const int  q0   = qt * BM;
    const long tok0 = (long)b * S;
    const int  qrow = q0 + wid * 32 + l32;    // the q-row this lane owns
    constexpr int KH_D = KH_ * D_;

    // ---- hoisted staging bases
    // K: row = (tid>>5) + it*8 (it 0..15), f32x4 chunk = tid&31
    const float* kbase = kg + (((long)(tok0 + (tid >> 5))) * KH_ + kh) * D_
                            + (tid & 31) * 4;
    // V: key = tid&127, d-chunks (tid>>7)*16 + it (it 0..15), d = chunk*4
    const float* vbase = vg + (((long)(tok0 + (tid & 127))) * KH_ + kh) * D_
                            + (tid >> 7) * 64;
    bf16_t* kw = &lds_k[(tid >> 5) * K_STRIDE + (tid & 31) * 4];
    bf16_t* vw = &lds_v[(tid >> 7) * 64 * V_STRIDE + (tid & 127)];

    // ---- Q fragments (B-layout, 32x32x16: lane holds Q[q=l32][dk*16+8*hi+j])
    bf16x8 qfrag[8];
    {
        const float* qp = qg + ((tok0 + qrow) * H_ + h) * D_;
        #pragma unroll
        for (int dk = 0; dk < 8; ++dk) {
            f32x4 a = *reinterpret_cast<const f32x4*>(qp + dk * 16 + 8 * hi);
            f32x4 c = *reinterpret_cast<const f32x4*>(qp + dk * 16 + 8 * hi + 4);
            #pragma unroll
            for (int j = 0; j < 4; ++j) {
                qfrag[dk][j]     = (bf16_t)a[j];
                qfrag[dk][j + 4] = (bf16_t)c[j];
            }
        }
    }

    // O^T accumulators: oacc[dt] C-layout, d = dt*32 + (reg&3)+8*(reg>>2)+4*hi
    f32x16 oacc[4];
    #pragma unroll
    for (int i = 0; i < 4; ++i)
        #pragma unroll
        for (int e = 0; e < 16; ++e) oacc[i][e] = 0.f;
    float m_i = NEG_INIT, l_i = 0.f;

    const int nkt = qt + 1;              // causal: k-tiles up to the diagonal

    for (int kt = 0; kt < nkt; ++kt) {
        const int kst = kt * BN;
        __syncthreads();                  // prior iter's LDS reads done

        // ---- stage K tile [128][128] fp32 -> bf16 LDS
        {
            const float* kp = kbase + (long)kst * KH_D;
            #pragma unroll
            for (int it = 0; it < 16; ++it) {
                f32x4 t = *reinterpret_cast<const f32x4*>(kp + it * 8 * KH_D);
                bf16x4 w;
                w[0] = (bf16_t)t[0]; w[1] = (bf16_t)t[1];
                w[2] = (bf16_t)t[2]; w[3] = (bf16_t)t[3];
                *reinterpret_cast<bf16x4*>(&kw[it * 8 * K_STRIDE]) = w;
            }
        }
        // ---- stage V transposed: lds_v[d][key]
        {
            const float* vp = vbase + (long)kst * KH_D;
            #pragma unroll
            for (int it = 0; it < 16; ++it) {
                f32x4 t = *reinterpret_cast<const f32x4*>(vp + it * 4);
                #pragma unroll
                for (int j = 0; j < 4; ++j)
                    vw[(it * 4 + j) * V_STRIDE] = (bf16_t)t[j];
            }
        }
        __syncthreads();

        // ---- S^T = K Q^T  (32x32x16; per wave: 128 keys x 32 q-rows)
        f32x16 s[4];
        __builtin_amdgcn_s_setprio(1);
        #pragma unroll
        for (int kb = 0; kb < 4; ++kb) {
            f32x16 acc;
            #pragma unroll
            for (int e = 0; e < 16; ++e) acc[e] = 0.f;
            #pragma unroll
            for (int dk = 0; dk < 8; ++dk) {
                bf16x8 kf = *reinterpret_cast<const bf16x8*>(
                    &lds_k[(kb * 32 + l32) * K_STRIDE + dk * 16 + 8 * hi]);
                acc = __builtin_amdgcn_mfma_f32_32x32x16_bf16(kf, qfrag[dk], acc, 0, 0, 0);
            }
            s[kb] = acc;  // key = kst+kb*32+(r&3)+8*(r>>2)+4*hi, q = l32
        }
        __builtin_amdgcn_s_setprio(0);

        // ---- mask + scale (per-lane; lane owns row qrow, 64 of 128 keys)
        if (kt == qt) {                   // only the diagonal tile masks
            #pragma unroll
            for (int kb = 0; kb < 4; ++kb)
                #pragma unroll
                for (int r = 0; r < 16; ++r) {
                    const int key = kst + kb * 32 + (r & 3) + 8 * (r >> 2) + 4 * hi;
                    float x = s[kb][r] * SCALE;
                    s[kb][r] = (key > qrow) ? NEG_MASK : x;
                }
        } else {
            #pragma unroll
            for (int kb = 0; kb < 4; ++kb)
                #pragma unroll
                for (int r = 0; r < 16; ++r)
                    s[kb][r] *= SCALE;
        }

        // ---- online softmax: 64 in-reg values + 1 shfl (partner half)
        float mx = s[0][0];
        #pragma unroll
        for (int kb = 0; kb < 4; ++kb)
            #pragma unroll
            for (int r = 0; r < 16; ++r) mx = fmaxf(mx, s[kb][r]);
        mx = fmaxf(mx, __shfl_xor(mx, 32));

        float mn_use = m_i;
        if (!__all(mx - m_i <= DEFER_THR)) {     // T13 defer-max
            const float mn    = fmaxf(m_i, mx);
            const float alpha = __expf(m_i - mn);
            l_i *= alpha;
            m_i = mn;
            mn_use = mn;
            #pragma unroll
            for (int dt = 0; dt < 4; ++dt)
                #pragma unroll
                for (int e = 0; e < 16; ++e)
                    oacc[dt][e] *= alpha;
        }

        // ---- exp + row-sum + pack per kb (s[kb] dies into Pu[kb])
        // Pu[kb][i] = keys kb*32 + 8*(i>>1) + 4*hi + 2*(i&1) + {0,1} (q=l32)
        unsigned Pu[4][8];
        float rs = 0.f;
        #pragma unroll
        for (int kb = 0; kb < 4; ++kb)
            #pragma unroll
            for (int i = 0; i < 8; ++i) {
                float p0 = __expf(s[kb][2 * i]     - mn_use);
                float p1 = __expf(s[kb][2 * i + 1] - mn_use);
                rs += p0 + p1;
                bf16x2 t;
                t[0] = (bf16_t)p0;
                t[1] = (bf16_t)p1;
                Pu[kb][i] = __builtin_bit_cast(unsigned, t);
            }
        rs += __shfl_xor(rs, 32);
        l_i += rs;

        // ---- O^T += V^T P^T  (32x32x16), ks-outer with lazy pf build:
        // per ks: 2 shfl_xor(32) + 4 selects -> one live pf (4 regs).
        __builtin_amdgcn_s_setprio(1);
        #pragma unroll
        for (int ks = 0; ks < 8; ++ks) {
            const int kb = ks >> 1, b4 = 4 * (ks & 1);
            unsigned v0 = hi ? Pu[kb][b4 + 0] : Pu[kb][b4 + 2];
            unsigned v1 = hi ? Pu[kb][b4 + 1] : Pu[kb][b4 + 3];
            unsigned x0 = (unsigned)__shfl_xor((int)v0, 32);
            unsigned x1 = (unsigned)__shfl_xor((int)v1, 32);
            u32x4 pu;
            pu[0] = hi ? x0 : Pu[kb][b4 + 0];
            pu[1] = hi ? x1 : Pu[kb][b4 + 1];
            pu[2] = hi ? Pu[kb][b4 + 2] : x0;
            pu[3] = hi ? Pu[kb][b4 + 3] : x1;
            bf16x8 pf = __builtin_bit_cast(bf16x8, pu);
            #pragma unroll
            for (int dt = 0; dt < 4; ++dt) {
                bf16x8 vf = *reinterpret_cast<const bf16x8*>(
                    &lds_v[(dt * 32 + l32) * V_STRIDE + ks * 16 + 8 * hi]);
                oacc[dt] = __builtin_amdgcn_mfma_f32_32x32x16_bf16(vf, pf, oacc[dt], 0, 0, 0);
            }
        }
        __builtin_amdgcn_s_setprio(0);
    }

    // ---- epilogue: O /= l, f32x4 stores; d = dt*32 + 8*g + 4*hi + {0..3}
    const float inv = 1.0f / l_i;
    float* op = og + ((tok0 + qrow) * H_ + h) * D_;
    #pragma unroll
    for (int dt = 0; dt < 4; ++dt)
        #pragma unroll
        for (int g = 0; g < 4; ++g) {
            f32x4 o;
            #pragma unroll
            for (int r = 0; r < 4; ++r) o[r] = oacc[dt][4 * g + r] * inv;
            *reinterpret_cast<f32x4*>(op + dt * 32 + 8 * g + 4 * hi) = o;
        }
}

extern "C" void kernel_launch(void* const* d_in, const int* in_sizes, int n_in,
                              void* d_out, int out_size, void* d_ws, size_t ws_size,
                              hipStream_t stream) {
    const float* q = (const float*)d_in[0];
    const float* k = (const float*)d_in[1];
    const float* v = (const float*)d_in[2];
    float* out = (float*)d_out;

    const int B = in_sizes[3] - 1;
    const int T = in_sizes[0] / (H_ * D_);
    const int S = T / B;
    const int nqt = S / BM;

    dim3 grid(nqt * H_ * B);
    fa_fwd<<<grid, 256, 0, stream>>>(q, k, v, out, S, nqt, B);
}

// Round 8
// 350.245 us; speedup vs baseline: 1.8521x; 1.0079x over previous
//
#include <hip/hip_runtime.h>
#include <hip/hip_bf16.h>

typedef __bf16 bf16_t;
typedef __bf16 bf16x2 __attribute__((ext_vector_type(2)));
typedef __bf16 bf16x4 __attribute__((ext_vector_type(4)));
typedef __bf16 bf16x8 __attribute__((ext_vector_type(8)));
typedef float f32x4 __attribute__((ext_vector_type(4)));
typedef float f32x16 __attribute__((ext_vector_type(16)));
typedef unsigned int u32x4 __attribute__((ext_vector_type(4)));

#define SCALE 0.08838834764831845f
#define NEG_MASK -1e10f      // matches reference; exp underflows to exact 0
#define NEG_INIT -3e38f      // running-max init; finite so no inf-inf paths
#define DEFER_THR 8.0f       // T13: tolerate m staleness up to e^8 in P

constexpr int H_ = 16;
constexpr int KH_ = 4;
constexpr int D_ = 128;
constexpr int BM = 128;  // q rows per workgroup (4 waves x 32 rows)
constexpr int BN = 128;  // keys per staged tile

constexpr int K_STRIDE = 136;  // K tile [128][128]+pad  (34816 B)
constexpr int V_STRIDE = 136;  // V^T tile [128][128]+pad (34816 B)
// LDS total 69632 B -> 2 WGs/CU.

// R9:  32x32 MFMA, BM=128, in-reg P exchange, LPT, (256,2): 266us,
//      no spill, conflicts 0, MfmaUtil 10.9.
// R10: BN=128 + quad-XCD swizzle: FLAT (262us). WRITE_SIZE 65->315MB =
//      ~28 regs/thread/tile scratch spill (s[4]+Pu[4] doubled live set);
//      spill ate the halved fixed costs. Swizzle DID work (FETCH 230->193).
// R11 (this round): keep BN=128 staging cadence (half the barriers/
//      staging), but compute in TWO 64-key chunks, each with R9's
//      proven-no-spill live set (s2[2]=32 regs, Pu2[2][8]=16 regs).
//      Math = two R9 iterations without re-staging. sched_barrier(0)
//      at the chunk boundary stops cross-chunk hoisting from
//      recreating the register pressure.
__global__ __launch_bounds__(256, 2)
void fa_fwd(const float* __restrict__ qg,
            const float* __restrict__ kg,
            const float* __restrict__ vg,
            float* __restrict__ og,
            int S, int nqt, int B)
{
    // ---- XCD swizzle (quad-grouping) + LPT decode
    const int nwg = gridDim.x;
    const int dsp = blockIdx.x;
    int gid;
    if ((nwg & 31) == 0) {
        const int xcd  = dsp & 7;
        const int slot = dsp >> 3;
        gid = 4 * (xcd + 8 * (slot >> 2)) + (slot & 3);
    } else {
        gid = dsp;
    }
    const int hbN  = H_ * B;
    const int rank = gid / hbN;          // 0 = most work (LPT)
    const int hb   = gid - rank * hbN;
    const int h    = hb & (H_ - 1);
    const int b    = hb >> 4;            // H_ == 16
    const int qt   = (nqt - 1) - rank;
    const int kh   = h / (H_ / KH_);     // GQA: 4 q-heads per kv-head

    const int tid  = threadIdx.x;
    const int wid  = tid >> 6;
    const int lane = tid & 63;
    const int l32  = lane & 31;
    const int hi   = lane >> 5;          // half-group within wave

    __shared__ bf16_t lds_k[BN * K_STRIDE];
    __shared__ bf16_t lds_v[D_ * V_STRIDE];   // transposed: [d][key]

    const int  q0   = qt * BM;
    const long tok0 = (long)b * S;
    const int  qrow = q0 + wid * 32 + l32;    // the q-row this lane owns
    constexpr int KH_D = KH_ * D_;

    // ---- hoisted staging bases
    // K: row = (tid>>5) + it*8 (it 0..15), f32x4 chunk = tid&31
    const float* kbase = kg + (((long)(tok0 + (tid >> 5))) * KH_ + kh) * D_
                            + (tid & 31) * 4;
    // V: key = tid&127, d-chunks (tid>>7)*16 + it (it 0..15), d = chunk*4
    const float* vbase = vg + (((long)(tok0 + (tid & 127))) * KH_ + kh) * D_
                            + (tid >> 7) * 64;
    bf16_t* kw = &lds_k[(tid >> 5) * K_STRIDE + (tid & 31) * 4];
    bf16_t* vw = &lds_v[(tid >> 7) * 64 * V_STRIDE + (tid & 127)];

    // ---- Q fragments (B-layout, 32x32x16: lane holds Q[q=l32][dk*16+8*hi+j])
    bf16x8 qfrag[8];
    {
        const float* qp = qg + ((tok0 + qrow) * H_ + h) * D_;
        #pragma unroll
        for (int dk = 0; dk < 8; ++dk) {
            f32x4 a = *reinterpret_cast<const f32x4*>(qp + dk * 16 + 8 * hi);
            f32x4 c = *reinterpret_cast<const f32x4*>(qp + dk * 16 + 8 * hi + 4);
            #pragma unroll
            for (int j = 0; j < 4; ++j) {
                qfrag[dk][j]     = (bf16_t)a[j];
                qfrag[dk][j + 4] = (bf16_t)c[j];
            }
        }
    }

    // O^T accumulators: oacc[dt] C-layout, d = dt*32 + (reg&3)+8*(reg>>2)+4*hi
    f32x16 oacc[4];
    #pragma unroll
    for (int i = 0; i < 4; ++i)
        #pragma unroll
        for (int e = 0; e < 16; ++e) oacc[i][e] = 0.f;
    float m_i = NEG_INIT, l_i = 0.f;

    const int nkt = qt + 1;              // causal: k-tiles up to the diagonal

    for (int kt = 0; kt < nkt; ++kt) {
        const int kst = kt * BN;
        __syncthreads();                  // prior iter's LDS reads done

        // ---- stage K tile [128][128] fp32 -> bf16 LDS
        {
            const float* kp = kbase + (long)kst * KH_D;
            #pragma unroll
            for (int it = 0; it < 16; ++it) {
                f32x4 t = *reinterpret_cast<const f32x4*>(kp + it * 8 * KH_D);
                bf16x4 w;
                w[0] = (bf16_t)t[0]; w[1] = (bf16_t)t[1];
                w[2] = (bf16_t)t[2]; w[3] = (bf16_t)t[3];
                *reinterpret_cast<bf16x4*>(&kw[it * 8 * K_STRIDE]) = w;
            }
        }
        // ---- stage V transposed: lds_v[d][key]
        {
            const float* vp = vbase + (long)kst * KH_D;
            #pragma unroll
            for (int it = 0; it < 16; ++it) {
                f32x4 t = *reinterpret_cast<const f32x4*>(vp + it * 4);
                #pragma unroll
                for (int j = 0; j < 4; ++j)
                    vw[(it * 4 + j) * V_STRIDE] = (bf16_t)t[j];
            }
        }
        __syncthreads();

        // ---- compute in two 64-key chunks (R9's live set each; the
        // sched_barrier at the end of each chunk prevents cross-chunk
        // hoisting that would re-inflate register pressure -> spill)
        #pragma unroll
        for (int ch = 0; ch < 2; ++ch) {
            // ---- S^T = K Q^T for this chunk (keys ch*64 .. ch*64+63)
            f32x16 s2[2];
            __builtin_amdgcn_s_setprio(1);
            #pragma unroll
            for (int kk = 0; kk < 2; ++kk) {
                const int kb = 2 * ch + kk;
                f32x16 acc;
                #pragma unroll
                for (int e = 0; e < 16; ++e) acc[e] = 0.f;
                #pragma unroll
                for (int dk = 0; dk < 8; ++dk) {
                    bf16x8 kf = *reinterpret_cast<const bf16x8*>(
                        &lds_k[(kb * 32 + l32) * K_STRIDE + dk * 16 + 8 * hi]);
                    acc = __builtin_amdgcn_mfma_f32_32x32x16_bf16(kf, qfrag[dk], acc, 0, 0, 0);
                }
                s2[kk] = acc;  // key = kst+kb*32+(r&3)+8*(r>>2)+4*hi, q=l32
            }
            __builtin_amdgcn_s_setprio(0);

            // ---- mask + scale
            if (kt == qt) {               // only the diagonal tile masks
                #pragma unroll
                for (int kk = 0; kk < 2; ++kk)
                    #pragma unroll
                    for (int r = 0; r < 16; ++r) {
                        const int key = kst + (2 * ch + kk) * 32
                                      + (r & 3) + 8 * (r >> 2) + 4 * hi;
                        float x = s2[kk][r] * SCALE;
                        s2[kk][r] = (key > qrow) ? NEG_MASK : x;
                    }
            } else {
                #pragma unroll
                for (int kk = 0; kk < 2; ++kk)
                    #pragma unroll
                    for (int r = 0; r < 16; ++r)
                        s2[kk][r] *= SCALE;
            }

            // ---- online softmax (32 in-reg values + 1 shfl)
            float mx = s2[0][0];
            #pragma unroll
            for (int kk = 0; kk < 2; ++kk)
                #pragma unroll
                for (int r = 0; r < 16; ++r) mx = fmaxf(mx, s2[kk][r]);
            mx = fmaxf(mx, __shfl_xor(mx, 32));

            float mn_use = m_i;
            if (!__all(mx - m_i <= DEFER_THR)) {     // T13 defer-max
                const float mn    = fmaxf(m_i, mx);
                const float alpha = __expf(m_i - mn);
                l_i *= alpha;
                m_i = mn;
                mn_use = mn;
                #pragma unroll
                for (int dt = 0; dt < 4; ++dt)
                    #pragma unroll
                    for (int e = 0; e < 16; ++e)
                        oacc[dt][e] *= alpha;
            }

            // ---- exp + row-sum + pack (s2 dies into Pu2)
            // Pu2[kk][i] = keys (2ch+kk)*32 + 8*(i>>1) + 4*hi + 2*(i&1)+{0,1}
            unsigned Pu2[2][8];
            float rs = 0.f;
            #pragma unroll
            for (int kk = 0; kk < 2; ++kk)
                #pragma unroll
                for (int i = 0; i < 8; ++i) {
                    float p0 = __expf(s2[kk][2 * i]     - mn_use);
                    float p1 = __expf(s2[kk][2 * i + 1] - mn_use);
                    rs += p0 + p1;
                    bf16x2 t;
                    t[0] = (bf16_t)p0;
                    t[1] = (bf16_t)p1;
                    Pu2[kk][i] = __builtin_bit_cast(unsigned, t);
                }
            rs += __shfl_xor(rs, 32);
            l_i += rs;

            // ---- O^T += V^T P^T for this chunk (global ks = 4*ch + ksl)
            __builtin_amdgcn_s_setprio(1);
            #pragma unroll
            for (int ksl = 0; ksl < 4; ++ksl) {
                const int kk = ksl >> 1, b4 = 4 * (ksl & 1);
                const int ks = 4 * ch + ksl;
                unsigned v0 = hi ? Pu2[kk][b4 + 0] : Pu2[kk][b4 + 2];
                unsigned v1 = hi ? Pu2[kk][b4 + 1] : Pu2[kk][b4 + 3];
                unsigned x0 = (unsigned)__shfl_xor((int)v0, 32);
                unsigned x1 = (unsigned)__shfl_xor((int)v1, 32);
                u32x4 pu;
                pu[0] = hi ? x0 : Pu2[kk][b4 + 0];
                pu[1] = hi ? x1 : Pu2[kk][b4 + 1];
                pu[2] = hi ? Pu2[kk][b4 + 2] : x0;
                pu[3] = hi ? Pu2[kk][b4 + 3] : x1;
                bf16x8 pf = __builtin_bit_cast(bf16x8, pu);
                #pragma unroll
                for (int dt = 0; dt < 4; ++dt) {
                    bf16x8 vf = *reinterpret_cast<const bf16x8*>(
                        &lds_v[(dt * 32 + l32) * V_STRIDE + ks * 16 + 8 * hi]);
                    oacc[dt] = __builtin_amdgcn_mfma_f32_32x32x16_bf16(vf, pf, oacc[dt], 0, 0, 0);
                }
            }
            __builtin_amdgcn_s_setprio(0);

            // pin: do not hoist next chunk's QK^T above this point
            __builtin_amdgcn_sched_barrier(0);
        }
    }

    // ---- epilogue: O /= l, f32x4 stores; d = dt*32 + 8*g + 4*hi + {0..3}
    const float inv = 1.0f / l_i;
    float* op = og + ((tok0 + qrow) * H_ + h) * D_;
    #pragma unroll
    for (int dt = 0; dt < 4; ++dt)
        #pragma unroll
        for (int g = 0; g < 4; ++g) {
            f32x4 o;
            #pragma unroll
            for (int r = 0; r < 4; ++r) o[r] = oacc[dt][4 * g + r] * inv;
            *reinterpret_cast<f32x4*>(op + dt * 32 + 8 * g + 4 * hi) = o;
        }
}

extern "C" void kernel_launch(void* const* d_in, const int* in_sizes, int n_in,
                              void* d_out, int out_size, void* d_ws, size_t ws_size,
                              hipStream_t stream) {
    const float* q = (const float*)d_in[0];
    const float* k = (const float*)d_in[1];
    const float* v = (const float*)d_in[2];
    float* out = (float*)d_out;

    const int B = in_sizes[3] - 1;
    const int T = in_sizes[0] / (H_ * D_);
    const int S = T / B;
    const int nqt = S / BM;

    dim3 grid(nqt * H_ * B);
    fa_fwd<<<grid, 256, 0, stream>>>(q, k, v, out, S, nqt, B);
}

// Round 9
// 337.479 us; speedup vs baseline: 1.9222x; 1.0378x over previous
//
#include <hip/hip_runtime.h>
#include <hip/hip_bf16.h>

typedef __bf16 bf16_t;
typedef __bf16 bf16x2 __attribute__((ext_vector_type(2)));
typedef __bf16 bf16x8 __attribute__((ext_vector_type(8)));
typedef float f32x4 __attribute__((ext_vector_type(4)));
typedef float f32x16 __attribute__((ext_vector_type(16)));
typedef unsigned int u32x4 __attribute__((ext_vector_type(4)));

#define SCALE 0.08838834764831845f
#define NEG_MASK -1e10f
#define NEG_INIT -3e38f
#define DEFER_THR 8.0f

constexpr int H_ = 16;
constexpr int KH_ = 4;
constexpr int D_ = 128;
constexpr int BM = 128;  // q rows per workgroup (4 waves x 32 rows)
constexpr int BN = 64;   // keys per staged tile

// R9/R10/R11 all ~263-266us with pipes <25%: flat across spill removal and
// traffic halving -> limiter is critical-path latency at 2 WGs/CU with
// in-wave staging (loads+cvt+scatter between barriers).
// R12: prepass converts K (bf16, chunk-XOR-swizzled) and V (bf16,
// TRANSPOSED [kh][d][s], swizzled) into d_ws. Main kernel stages via
// global_load_lds DMA: staging regs, 128 cvts and the 64-op V-scatter
// disappear; LDS 32KB (swizzle replaces pads, T2); live set fits
// (256,3) -> 3 WGs/CU.

// ---- prepass 1: K fp32 [T*KH][128] -> bf16 ws, 16B chunks XOR'd by token&15
__global__ __launch_bounds__(256)
void prep_k(const float* __restrict__ kg, bf16_t* __restrict__ wk, int nchunks)
{
    int i = blockIdx.x * 256 + threadIdx.x;
    if (i >= nchunks) return;
    int tk = i >> 4, c = i & 15;          // row (token*KH+kh), 16B chunk
    int tok = tk >> 2;                    // KH_ == 4
    const float* src = kg + (long)tk * 128 + c * 8;
    f32x4 a = *reinterpret_cast<const f32x4*>(src);
    f32x4 b = *reinterpret_cast<const f32x4*>(src + 4);
    bf16x8 w;
    #pragma unroll
    for (int j = 0; j < 4; ++j) { w[j] = (bf16_t)a[j]; w[j + 4] = (bf16_t)b[j]; }
    int cp = c ^ (tok & 15);              // bake read-side swizzle
    *reinterpret_cast<bf16x8*>(wk + (long)tk * 128 + cp * 8) = w;
}

// ---- prepass 2: V fp32 [T][KH][128] -> bf16 ws TRANSPOSED [b*KH+kh][d][s],
// 16B chunks within each 64-key window XOR'd by d&7
__global__ __launch_bounds__(256)
void prep_v(const float* __restrict__ vg, bf16_t* __restrict__ wv, int S)
{
    __shared__ bf16_t lt[64 * 130];
    const int tt  = blockIdx.x >> 2;      // 64-token tile
    const int kh  = blockIdx.x & 3;
    const int tid = threadIdx.x;
    const long t0 = (long)tt * 64;
    const int  b  = (int)(t0 / S);
    const int  s0 = (int)(t0 - (long)b * S);
    #pragma unroll
    for (int u = 0; u < 8; ++u) {
        int idx = u * 256 + tid;          // 0..2047
        int tr = idx >> 5, c4 = idx & 31;
        f32x4 t = *reinterpret_cast<const f32x4*>(
            vg + ((t0 + tr) * KH_ + kh) * D_ + c4 * 4);
        bf16_t* dst = &lt[tr * 130 + c4 * 4];
        dst[0] = (bf16_t)t[0]; dst[1] = (bf16_t)t[1];
        dst[2] = (bf16_t)t[2]; dst[3] = (bf16_t)t[3];
    }
    __syncthreads();
    #pragma unroll
    for (int u = 0; u < 4; ++u) {
        int idx = u * 256 + tid;          // 0..1023
        int d = idx >> 3, cc = idx & 7;   // d row, 8-key chunk
        bf16x8 w;
        #pragma unroll
        for (int j = 0; j < 8; ++j) w[j] = lt[(cc * 8 + j) * 130 + d];
        long base = ((long)(b * KH_ + kh) * D_ + d) * S + s0;
        *reinterpret_cast<bf16x8*>(wv + base + (cc ^ (d & 7)) * 8) = w;
    }
}

__global__ __launch_bounds__(256, 3)
void fa_fwd(const float* __restrict__ qg,
            const bf16_t* __restrict__ wk,
            const bf16_t* __restrict__ wv,
            float* __restrict__ og,
            int S, int nqt, int B)
{
    // ---- quad-XCD swizzle + LPT decode
    const int nwg = gridDim.x;
    const int dsp = blockIdx.x;
    int gid;
    if ((nwg & 31) == 0) {
        const int xcd  = dsp & 7;
        const int slot = dsp >> 3;
        gid = 4 * (xcd + 8 * (slot >> 2)) + (slot & 3);
    } else {
        gid = dsp;
    }
    const int hbN  = H_ * B;
    const int rank = gid / hbN;
    const int hb   = gid - rank * hbN;
    const int h    = hb & (H_ - 1);
    const int b    = hb >> 4;
    const int qt   = (nqt - 1) - rank;
    const int kh   = h / (H_ / KH_);

    const int tid  = threadIdx.x;
    const int wid  = tid >> 6;
    const int lane = tid & 63;
    const int l32  = lane & 31;
    const int hi   = lane >> 5;

    __shared__ bf16_t lds_k[BN * D_];     // [64][128] bf16, swizzled, 16KB
    __shared__ bf16_t lds_v[D_ * BN];     // [128][64] bf16, swizzled, 16KB

    const int  q0   = qt * BM;
    const long tok0 = (long)b * S;
    const int  qrow = q0 + wid * 32 + l32;

    // ---- Q fragments (fp32 global -> bf16 regs, once)
    bf16x8 qfrag[8];
    {
        const float* qp = qg + ((tok0 + qrow) * H_ + h) * D_;
        #pragma unroll
        for (int dk = 0; dk < 8; ++dk) {
            f32x4 a = *reinterpret_cast<const f32x4*>(qp + dk * 16 + 8 * hi);
            f32x4 c = *reinterpret_cast<const f32x4*>(qp + dk * 16 + 8 * hi + 4);
            #pragma unroll
            for (int j = 0; j < 4; ++j) {
                qfrag[dk][j]     = (bf16_t)a[j];
                qfrag[dk][j + 4] = (bf16_t)c[j];
            }
        }
    }

    f32x16 oacc[4];
    #pragma unroll
    for (int i = 0; i < 4; ++i)
        #pragma unroll
        for (int e = 0; e < 16; ++e) oacc[i][e] = 0.f;
    float m_i = NEG_INIT, l_i = 0.f;

    const bf16_t* kseq = wk + (tok0 * KH_ + kh) * D_;              // K rows
    const bf16_t* vrow = wv + (long)(b * KH_ + kh) * D_ * S;       // V^T rows

    const int nkt = 2 * qt + 2;           // BN=64: tiles up to diagonal

    for (int kt = 0; kt < nkt; ++kt) {
        const int kst = kt * BN;
        __syncthreads();                  // prior iter's LDS reads done

        // ---- stage K via global_load_lds: 4 x 1KB per wave (linear dest;
        // swizzle pre-baked in ws)
        #pragma unroll
        for (int i = 0; i < 4; ++i) {
            const int row = wid * 16 + i * 4 + (lane >> 4);
            const bf16_t* src = kseq + ((long)(kst + row) * KH_) * D_
                                + (lane & 15) * 8;
            __builtin_amdgcn_global_load_lds(
                (const __attribute__((address_space(1))) unsigned int*)src,
                (__attribute__((address_space(3))) unsigned int*)
                    ((char*)lds_k + row * 256 + (lane & 15) * 16),
                16, 0, 0);
        }
        // ---- stage V^T: rows d, 128B each; 4 x 1KB per wave
        #pragma unroll
        for (int i = 0; i < 4; ++i) {
            const int d = wid * 32 + i * 8 + (lane >> 3);
            const bf16_t* src = vrow + (long)d * S + kst + (lane & 7) * 8;
            __builtin_amdgcn_global_load_lds(
                (const __attribute__((address_space(1))) unsigned int*)src,
                (__attribute__((address_space(3))) unsigned int*)
                    ((char*)lds_v + d * 128 + (lane & 7) * 16),
                16, 0, 0);
        }
        __syncthreads();                  // compiler drains vmcnt before bar

        // fully-masked wave on trailing diagonal tiles: skip compute
        if (kst > q0 + wid * 32 + 31) continue;

        // ---- S^T = K Q^T (32x32x16), swizzled K reads (2-way = free)
        f32x16 s[2];
        __builtin_amdgcn_s_setprio(1);
        #pragma unroll
        for (int kb = 0; kb < 2; ++kb) {
            f32x16 acc;
            #pragma unroll
            for (int e = 0; e < 16; ++e) acc[e] = 0.f;
            const int row = kb * 32 + l32;
            #pragma unroll
            for (int dk = 0; dk < 8; ++dk) {
                const int byte = row * 256
                               + ((dk * 32 + 16 * hi) ^ ((row & 15) << 4));
                bf16x8 kf = *reinterpret_cast<const bf16x8*>(
                    (const char*)lds_k + byte);
                acc = __builtin_amdgcn_mfma_f32_32x32x16_bf16(kf, qfrag[dk], acc, 0, 0, 0);
            }
            s[kb] = acc;  // key = kst+kb*32+(r&3)+8*(r>>2)+4*hi, q = l32
        }
        __builtin_amdgcn_s_setprio(0);

        // ---- mask + scale
        if (kst + BN - 1 > q0 + wid * 32) {
            #pragma unroll
            for (int kb = 0; kb < 2; ++kb)
                #pragma unroll
                for (int r = 0; r < 16; ++r) {
                    const int key = kst + kb * 32 + (r & 3) + 8 * (r >> 2) + 4 * hi;
                    float x = s[kb][r] * SCALE;
                    s[kb][r] = (key > qrow) ? NEG_MASK : x;
                }
        } else {
            #pragma unroll
            for (int kb = 0; kb < 2; ++kb)
                #pragma unroll
                for (int r = 0; r < 16; ++r)
                    s[kb][r] *= SCALE;
        }

        // ---- online softmax (32 in-reg + 1 shfl)
        float mx = s[0][0];
        #pragma unroll
        for (int kb = 0; kb < 2; ++kb)
            #pragma unroll
            for (int r = 0; r < 16; ++r) mx = fmaxf(mx, s[kb][r]);
        mx = fmaxf(mx, __shfl_xor(mx, 32));

        float mn_use = m_i;
        if (!__all(mx - m_i <= DEFER_THR)) {     // T13 defer-max
            const float mn    = fmaxf(m_i, mx);
            const float alpha = __expf(m_i - mn);
            l_i *= alpha;
            m_i = mn;
            mn_use = mn;
            #pragma unroll
            for (int dt = 0; dt < 4; ++dt)
                #pragma unroll
                for (int e = 0; e < 16; ++e)
                    oacc[dt][e] *= alpha;
        }

        // ---- exp + row-sum + pack (s dies into Pu)
        unsigned Pu[2][8];
        float rs = 0.f;
        #pragma unroll
        for (int kb = 0; kb < 2; ++kb)
            #pragma unroll
            for (int i = 0; i < 8; ++i) {
                float p0 = __expf(s[kb][2 * i]     - mn_use);
                float p1 = __expf(s[kb][2 * i + 1] - mn_use);
                rs += p0 + p1;
                bf16x2 t;
                t[0] = (bf16_t)p0;
                t[1] = (bf16_t)p1;
                Pu[kb][i] = __builtin_bit_cast(unsigned, t);
            }
        rs += __shfl_xor(rs, 32);
        l_i += rs;

        // ---- O^T += V^T P^T, lazy pf build; swizzled V reads (4-way)
        __builtin_amdgcn_s_setprio(1);
        #pragma unroll
        for (int ksl = 0; ksl < 4; ++ksl) {
            const int kk = ksl >> 1, b4 = 4 * (ksl & 1);
            unsigned v0 = hi ? Pu[kk][b4 + 0] : Pu[kk][b4 + 2];
            unsigned v1 = hi ? Pu[kk][b4 + 1] : Pu[kk][b4 + 3];
            unsigned x0 = (unsigned)__shfl_xor((int)v0, 32);
            unsigned x1 = (unsigned)__shfl_xor((int)v1, 32);
            u32x4 pu;
            pu[0] = hi ? x0 : Pu[kk][b4 + 0];
            pu[1] = hi ? x1 : Pu[kk][b4 + 1];
            pu[2] = hi ? Pu[kk][b4 + 2] : x0;
            pu[3] = hi ? Pu[kk][b4 + 3] : x1;
            bf16x8 pf = __builtin_bit_cast(bf16x8, pu);
            #pragma unroll
            for (int dt = 0; dt < 4; ++dt) {
                const int d = dt * 32 + l32;
                const int byte = d * 128
                               + ((ksl * 32 + 16 * hi) ^ ((d & 7) << 4));
                bf16x8 vf = *reinterpret_cast<const bf16x8*>(
                    (const char*)lds_v + byte);
                oacc[dt] = __builtin_amdgcn_mfma_f32_32x32x16_bf16(vf, pf, oacc[dt], 0, 0, 0);
            }
        }
        __builtin_amdgcn_s_setprio(0);
    }

    // ---- epilogue
    const float inv = 1.0f / l_i;
    float* op = og + ((tok0 + qrow) * H_ + h) * D_;
    #pragma unroll
    for (int dt = 0; dt < 4; ++dt)
        #pragma unroll
        for (int g = 0; g < 4; ++g) {
            f32x4 o;
            #pragma unroll
            for (int r = 0; r < 4; ++r) o[r] = oacc[dt][4 * g + r] * inv;
            *reinterpret_cast<f32x4*>(op + dt * 32 + 8 * g + 4 * hi) = o;
        }
}

extern "C" void kernel_launch(void* const* d_in, const int* in_sizes, int n_in,
                              void* d_out, int out_size, void* d_ws, size_t ws_size,
                              hipStream_t stream) {
    const float* q = (const float*)d_in[0];
    const float* k = (const float*)d_in[1];
    const float* v = (const float*)d_in[2];
    float* out = (float*)d_out;

    const int B = in_sizes[3] - 1;
    const int T = in_sizes[0] / (H_ * D_);
    const int S = T / B;
    const int nqt = S / BM;

    bf16_t* wk = (bf16_t*)d_ws;                       // [T*KH][128] bf16
    bf16_t* wv = wk + (size_t)T * KH_ * D_;           // [B*KH][128][S] bf16

    const int nchunks = T * KH_ * 16;                 // 16B chunks in K
    prep_k<<<(nchunks + 255) / 256, 256, 0, stream>>>(k, wk, nchunks);
    prep_v<<<(T / 64) * KH_, 256, 0, stream>>>(v, wv, S);

    dim3 grid(nqt * H_ * B);
    fa_fwd<<<grid, 256, 0, stream>>>(q, wk, wv, out, S, nqt, B);
}

// Round 10
// 281.979 us; speedup vs baseline: 2.3005x; 1.1968x over previous
//
#include <hip/hip_runtime.h>
#include <hip/hip_bf16.h>

typedef __bf16 bf16_t;
typedef __bf16 bf16x2 __attribute__((ext_vector_type(2)));
typedef __bf16 bf16x8 __attribute__((ext_vector_type(8)));
typedef float f32x4 __attribute__((ext_vector_type(4)));
typedef float f32x16 __attribute__((ext_vector_type(16)));
typedef unsigned int u32x4 __attribute__((ext_vector_type(4)));

#define SCALE 0.08838834764831845f
#define NEG_MASK -1e10f
#define NEG_INIT -3e38f
#define DEFER_THR 8.0f

constexpr int H_ = 16;
constexpr int KH_ = 4;
constexpr int D_ = 128;
constexpr int BM = 128;  // q rows per workgroup (4 waves x 32 rows)
constexpr int BN = 64;   // keys per staged tile

// R12: prepass (bf16 + baked swizzle + V^T) + global_load_lds staging:
//      263->227us. Occ 28.6, MfmaUtil 12.7, no spill. BUT FETCH 559MB =
//      17408 tiles x 32KB = ZERO L2 reuse on the DMA path, and the
//      stage -> barrier(vmcnt0 drain) -> compute order exposes the full
//      L3/HBM round-trip (~600-900cy) between barriers EVERY tile.
// R13 (this round): T3-minimum 2-phase pipeline.
//      Double-buffer LDS (2x32KB=64KB, 2 WGs/CU) and issue tile t+1's
//      8 global_load_lds BEFORE computing tile t; the barrier drain at
//      end-of-compute then waits on ~2500cy-old loads -> latency hidden.
//      One barrier per tile instead of two.

// ---- prepass 1: K fp32 [T*KH][128] -> bf16 ws, 16B chunks XOR'd by token&15
__global__ __launch_bounds__(256)
void prep_k(const float* __restrict__ kg, bf16_t* __restrict__ wk, int nchunks)
{
    int i = blockIdx.x * 256 + threadIdx.x;
    if (i >= nchunks) return;
    int tk = i >> 4, c = i & 15;          // row (token*KH+kh), 16B chunk
    int tok = tk >> 2;                    // KH_ == 4
    const float* src = kg + (long)tk * 128 + c * 8;
    f32x4 a = *reinterpret_cast<const f32x4*>(src);
    f32x4 b = *reinterpret_cast<const f32x4*>(src + 4);
    bf16x8 w;
    #pragma unroll
    for (int j = 0; j < 4; ++j) { w[j] = (bf16_t)a[j]; w[j + 4] = (bf16_t)b[j]; }
    int cp = c ^ (tok & 15);              // bake read-side swizzle
    *reinterpret_cast<bf16x8*>(wk + (long)tk * 128 + cp * 8) = w;
}

// ---- prepass 2: V fp32 [T][KH][128] -> bf16 ws TRANSPOSED [b*KH+kh][d][s],
// 16B chunks within each 64-key window XOR'd by d&7
__global__ __launch_bounds__(256)
void prep_v(const float* __restrict__ vg, bf16_t* __restrict__ wv, int S)
{
    __shared__ bf16_t lt[64 * 130];
    const int tt  = blockIdx.x >> 2;      // 64-token tile
    const int kh  = blockIdx.x & 3;
    const int tid = threadIdx.x;
    const long t0 = (long)tt * 64;
    const int  b  = (int)(t0 / S);
    const int  s0 = (int)(t0 - (long)b * S);
    #pragma unroll
    for (int u = 0; u < 8; ++u) {
        int idx = u * 256 + tid;          // 0..2047
        int tr = idx >> 5, c4 = idx & 31;
        f32x4 t = *reinterpret_cast<const f32x4*>(
            vg + ((t0 + tr) * KH_ + kh) * D_ + c4 * 4);
        bf16_t* dst = &lt[tr * 130 + c4 * 4];
        dst[0] = (bf16_t)t[0]; dst[1] = (bf16_t)t[1];
        dst[2] = (bf16_t)t[2]; dst[3] = (bf16_t)t[3];
    }
    __syncthreads();
    #pragma unroll
    for (int u = 0; u < 4; ++u) {
        int idx = u * 256 + tid;          // 0..1023
        int d = idx >> 3, cc = idx & 7;   // d row, 8-key chunk
        bf16x8 w;
        #pragma unroll
        for (int j = 0; j < 8; ++j) w[j] = lt[(cc * 8 + j) * 130 + d];
        long base = ((long)(b * KH_ + kh) * D_ + d) * S + s0;
        *reinterpret_cast<bf16x8*>(wv + base + (cc ^ (d & 7)) * 8) = w;
    }
}

__global__ __launch_bounds__(256, 3)
void fa_fwd(const float* __restrict__ qg,
            const bf16_t* __restrict__ wk,
            const bf16_t* __restrict__ wv,
            float* __restrict__ og,
            int S, int nqt, int B)
{
    // ---- quad-XCD swizzle + LPT decode
    const int nwg = gridDim.x;
    const int dsp = blockIdx.x;
    int gid;
    if ((nwg & 31) == 0) {
        const int xcd  = dsp & 7;
        const int slot = dsp >> 3;
        gid = 4 * (xcd + 8 * (slot >> 2)) + (slot & 3);
    } else {
        gid = dsp;
    }
    const int hbN  = H_ * B;
    const int rank = gid / hbN;
    const int hb   = gid - rank * hbN;
    const int h    = hb & (H_ - 1);
    const int b    = hb >> 4;
    const int qt   = (nqt - 1) - rank;
    const int kh   = h / (H_ / KH_);

    const int tid  = threadIdx.x;
    const int wid  = tid >> 6;
    const int lane = tid & 63;
    const int l32  = lane & 31;
    const int hi   = lane >> 5;

    __shared__ bf16_t lds_k[2][BN * D_];  // [64][128] bf16 swizzled, 16KB ea
    __shared__ bf16_t lds_v[2][D_ * BN];  // [128][64] bf16 swizzled, 16KB ea

    const int  q0   = qt * BM;
    const long tok0 = (long)b * S;
    const int  qrow = q0 + wid * 32 + l32;

    // ---- Q fragments (fp32 global -> bf16 regs, once)
    bf16x8 qfrag[8];
    {
        const float* qp = qg + ((tok0 + qrow) * H_ + h) * D_;
        #pragma unroll
        for (int dk = 0; dk < 8; ++dk) {
            f32x4 a = *reinterpret_cast<const f32x4*>(qp + dk * 16 + 8 * hi);
            f32x4 c = *reinterpret_cast<const f32x4*>(qp + dk * 16 + 8 * hi + 4);
            #pragma unroll
            for (int j = 0; j < 4; ++j) {
                qfrag[dk][j]     = (bf16_t)a[j];
                qfrag[dk][j + 4] = (bf16_t)c[j];
            }
        }
    }

    f32x16 oacc[4];
    #pragma unroll
    for (int i = 0; i < 4; ++i)
        #pragma unroll
        for (int e = 0; e < 16; ++e) oacc[i][e] = 0.f;
    float m_i = NEG_INIT, l_i = 0.f;

    const bf16_t* kseq = wk + (tok0 * KH_ + kh) * D_;              // K rows
    const bf16_t* vrow = wv + (long)(b * KH_ + kh) * D_ * S;       // V^T rows

    const int nkt = 2 * qt + 2;           // BN=64: tiles up to diagonal

    // issue-early DMA stage of one K/V tile into buffer bufidx
    auto STAGE = [&](int kstage, int bufidx) {
        #pragma unroll
        for (int i = 0; i < 4; ++i) {
            const int row = wid * 16 + i * 4 + (lane >> 4);
            const bf16_t* src = kseq + ((long)(kstage + row) * KH_) * D_
                                + (lane & 15) * 8;
            __builtin_amdgcn_global_load_lds(
                (const __attribute__((address_space(1))) unsigned int*)src,
                (__attribute__((address_space(3))) unsigned int*)
                    ((char*)&lds_k[bufidx][0] + row * 256 + (lane & 15) * 16),
                16, 0, 0);
        }
        #pragma unroll
        for (int i = 0; i < 4; ++i) {
            const int d = wid * 32 + i * 8 + (lane >> 3);
            const bf16_t* src = vrow + (long)d * S + kstage + (lane & 7) * 8;
            __builtin_amdgcn_global_load_lds(
                (const __attribute__((address_space(1))) unsigned int*)src,
                (__attribute__((address_space(3))) unsigned int*)
                    ((char*)&lds_v[bufidx][0] + d * 128 + (lane & 7) * 16),
                16, 0, 0);
        }
    };

    // ---- prologue: stage tile 0; barrier drains vmcnt
    STAGE(0, 0);
    __syncthreads();

    int cur = 0;
    for (int kt = 0; kt < nkt; ++kt) {
        const int kst = kt * BN;

        // ---- 2-phase: issue next tile's DMA BEFORE computing this one
        if (kt + 1 < nkt) STAGE(kst + BN, cur ^ 1);

        // fully-masked wave on trailing diagonal tiles: skip compute
        if (kst <= q0 + wid * 32 + 31) {
            const char* kbuf = (const char*)&lds_k[cur][0];
            const char* vbuf = (const char*)&lds_v[cur][0];

            // ---- S^T = K Q^T (32x32x16), swizzled K reads
            f32x16 s[2];
            __builtin_amdgcn_s_setprio(1);
            #pragma unroll
            for (int kb = 0; kb < 2; ++kb) {
                f32x16 acc;
                #pragma unroll
                for (int e = 0; e < 16; ++e) acc[e] = 0.f;
                const int row = kb * 32 + l32;
                #pragma unroll
                for (int dk = 0; dk < 8; ++dk) {
                    const int byte = row * 256
                                   + ((dk * 32 + 16 * hi) ^ ((row & 15) << 4));
                    bf16x8 kf = *reinterpret_cast<const bf16x8*>(kbuf + byte);
                    acc = __builtin_amdgcn_mfma_f32_32x32x16_bf16(kf, qfrag[dk], acc, 0, 0, 0);
                }
                s[kb] = acc;  // key = kst+kb*32+(r&3)+8*(r>>2)+4*hi, q = l32
            }
            __builtin_amdgcn_s_setprio(0);

            // ---- mask + scale
            if (kst + BN - 1 > q0 + wid * 32) {
                #pragma unroll
                for (int kb = 0; kb < 2; ++kb)
                    #pragma unroll
                    for (int r = 0; r < 16; ++r) {
                        const int key = kst + kb * 32 + (r & 3) + 8 * (r >> 2) + 4 * hi;
                        float x = s[kb][r] * SCALE;
                        s[kb][r] = (key > qrow) ? NEG_MASK : x;
                    }
            } else {
                #pragma unroll
                for (int kb = 0; kb < 2; ++kb)
                    #pragma unroll
                    for (int r = 0; r < 16; ++r)
                        s[kb][r] *= SCALE;
            }

            // ---- online softmax (32 in-reg + 1 shfl)
            float mx = s[0][0];
            #pragma unroll
            for (int kb = 0; kb < 2; ++kb)
                #pragma unroll
                for (int r = 0; r < 16; ++r) mx = fmaxf(mx, s[kb][r]);
            mx = fmaxf(mx, __shfl_xor(mx, 32));

            float mn_use = m_i;
            if (!__all(mx - m_i <= DEFER_THR)) {     // T13 defer-max
                const float mn    = fmaxf(m_i, mx);
                const float alpha = __expf(m_i - mn);
                l_i *= alpha;
                m_i = mn;
                mn_use = mn;
                #pragma unroll
                for (int dt = 0; dt < 4; ++dt)
                    #pragma unroll
                    for (int e = 0; e < 16; ++e)
                        oacc[dt][e] *= alpha;
            }

            // ---- exp + row-sum + pack (s dies into Pu)
            unsigned Pu[2][8];
            float rs = 0.f;
            #pragma unroll
            for (int kb = 0; kb < 2; ++kb)
                #pragma unroll
                for (int i = 0; i < 8; ++i) {
                    float p0 = __expf(s[kb][2 * i]     - mn_use);
                    float p1 = __expf(s[kb][2 * i + 1] - mn_use);
                    rs += p0 + p1;
                    bf16x2 t;
                    t[0] = (bf16_t)p0;
                    t[1] = (bf16_t)p1;
                    Pu[kb][i] = __builtin_bit_cast(unsigned, t);
                }
            rs += __shfl_xor(rs, 32);
            l_i += rs;

            // ---- O^T += V^T P^T, lazy pf build; swizzled V reads
            __builtin_amdgcn_s_setprio(1);
            #pragma unroll
            for (int ksl = 0; ksl < 4; ++ksl) {
                const int kk = ksl >> 1, b4 = 4 * (ksl & 1);
                unsigned v0 = hi ? Pu[kk][b4 + 0] : Pu[kk][b4 + 2];
                unsigned v1 = hi ? Pu[kk][b4 + 1] : Pu[kk][b4 + 3];
                unsigned x0 = (unsigned)__shfl_xor((int)v0, 32);
                unsigned x1 = (unsigned)__shfl_xor((int)v1, 32);
                u32x4 pu;
                pu[0] = hi ? x0 : Pu[kk][b4 + 0];
                pu[1] = hi ? x1 : Pu[kk][b4 + 1];
                pu[2] = hi ? Pu[kk][b4 + 2] : x0;
                pu[3] = hi ? Pu[kk][b4 + 3] : x1;
                bf16x8 pf = __builtin_bit_cast(bf16x8, pu);
                #pragma unroll
                for (int dt = 0; dt < 4; ++dt) {
                    const int d = dt * 32 + l32;
                    const int byte = d * 128
                                   + ((ksl * 32 + 16 * hi) ^ ((d & 7) << 4));
                    bf16x8 vf = *reinterpret_cast<const bf16x8*>(vbuf + byte);
                    oacc[dt] = __builtin_amdgcn_mfma_f32_32x32x16_bf16(vf, pf, oacc[dt], 0, 0, 0);
                }
            }
            __builtin_amdgcn_s_setprio(0);
        }

        // one barrier per tile: drains the prefetch (issued ~a compute-phase
        // ago) and fences this tile's LDS reads before the next overwrite
        __syncthreads();
        cur ^= 1;
    }

    // ---- epilogue
    const float inv = 1.0f / l_i;
    float* op = og + ((tok0 + qrow) * H_ + h) * D_;
    #pragma unroll
    for (int dt = 0; dt < 4; ++dt)
        #pragma unroll
        for (int g = 0; g < 4; ++g) {
            f32x4 o;
            #pragma unroll
            for (int r = 0; r < 4; ++r) o[r] = oacc[dt][4 * g + r] * inv;
            *reinterpret_cast<f32x4*>(op + dt * 32 + 8 * g + 4 * hi) = o;
        }
}

extern "C" void kernel_launch(void* const* d_in, const int* in_sizes, int n_in,
                              void* d_out, int out_size, void* d_ws, size_t ws_size,
                              hipStream_t stream) {
    const float* q = (const float*)d_in[0];
    const float* k = (const float*)d_in[1];
    const float* v = (const float*)d_in[2];
    float* out = (float*)d_out;

    const int B = in_sizes[3] - 1;
    const int T = in_sizes[0] / (H_ * D_);
    const int S = T / B;
    const int nqt = S / BM;

    bf16_t* wk = (bf16_t*)d_ws;                       // [T*KH][128] bf16
    bf16_t* wv = wk + (size_t)T * KH_ * D_;           // [B*KH][128][S] bf16

    const int nchunks = T * KH_ * 16;                 // 16B chunks in K
    prep_k<<<(nchunks + 255) / 256, 256, 0, stream>>>(k, wk, nchunks);
    prep_v<<<(T / 64) * KH_, 256, 0, stream>>>(v, wv, S);

    dim3 grid(nqt * H_ * B);
    fa_fwd<<<grid, 256, 0, stream>>>(q, wk, wv, out, S, nqt, B);
}

// Round 11
// 220.818 us; speedup vs baseline: 2.9376x; 1.2770x over previous
//
#include <hip/hip_runtime.h>
#include <hip/hip_bf16.h>

typedef __bf16 bf16_t;
typedef __bf16 bf16x2 __attribute__((ext_vector_type(2)));
typedef __bf16 bf16x8 __attribute__((ext_vector_type(8)));
typedef float f32x4 __attribute__((ext_vector_type(4)));
typedef float f32x16 __attribute__((ext_vector_type(16)));
typedef unsigned int u32x4 __attribute__((ext_vector_type(4)));

#define NEG_MASK -1e10f
#define NEG_INIT -3e38f
#define DEFER_THR2 11.5f     // base-2 domain; == e^8 bound
// SCALE * log2(e): fold into Q so exp2 is native v_exp_f32, no muls
#define QSC (0.08838834764831845f * 1.44269504088896f)

__device__ inline float exp2fast(float x) {
#if __has_builtin(__builtin_amdgcn_exp2f)
    return __builtin_amdgcn_exp2f(x);
#else
    return exp2f(x);
#endif
}

constexpr int H_ = 16;
constexpr int KH_ = 4;
constexpr int D_ = 128;
constexpr int BM = 128;  // q rows per workgroup (4 waves x 32 rows)
constexpr int BN = 32;   // keys per staged tile (R14: was 64)

// R13: 2-phase DMA prefetch + dbuf: 227->179.5us. FETCH 51MB, no spill.
//      Remaining: 6335cy/CU/tile vs ~2200cy max-pipe -> dependency stalls
//      at 8 waves/CU (LDS 64KB caps 2 WGs).
// R14: BN=32 dbuf -> LDS 32KB/WG -> 3 WGs/CU (12 waves, +50% overlap).
//      V gets a 2-level XOR baked layout (4 chunks/row needs d>>2 bits to
//      stay 4-way conflict). Base-2 softmax (QSC folded into Q; exp2
//      native). Sentinel: WRITE_SIZE>>70MB = spill under (256,3) cap.

// ---- prepass 1: K fp32 [T*KH][128] -> bf16 ws, 16B chunks XOR'd by token&15
__global__ __launch_bounds__(256)
void prep_k(const float* __restrict__ kg, bf16_t* __restrict__ wk, int nchunks)
{
    int i = blockIdx.x * 256 + threadIdx.x;
    if (i >= nchunks) return;
    int tk = i >> 4, c = i & 15;          // row (token*KH+kh), 16B chunk
    int tok = tk >> 2;                    // KH_ == 4
    const float* src = kg + (long)tk * 128 + c * 8;
    f32x4 a = *reinterpret_cast<const f32x4*>(src);
    f32x4 b = *reinterpret_cast<const f32x4*>(src + 4);
    bf16x8 w;
    #pragma unroll
    for (int j = 0; j < 4; ++j) { w[j] = (bf16_t)a[j]; w[j + 4] = (bf16_t)b[j]; }
    int cp = c ^ (tok & 15);              // bake read-side swizzle
    *reinterpret_cast<bf16x8*>(wk + (long)tk * 128 + cp * 8) = w;
}

// ---- prepass 2: V fp32 [T][KH][128] -> bf16 ws, layout [b*KH+kh][win][4096]
// per 32-key window: chunk m = g*16 + i*4 + (c ^ i ^ (g&3)), where
// d = g*4+i (0..127), c = 16B key-chunk (0..3). Gives 4-way-max LDS reads
// with a pure-linear DMA stage.
__global__ __launch_bounds__(256)
void prep_v(const float* __restrict__ vg, bf16_t* __restrict__ wv, int S)
{
    __shared__ bf16_t lt[64 * 130];
    const int tt  = blockIdx.x >> 2;      // 64-token tile
    const int kh  = blockIdx.x & 3;
    const int tid = threadIdx.x;
    const long t0 = (long)tt * 64;
    const int  b  = (int)(t0 / S);
    const int  s0 = (int)(t0 - (long)b * S);
    #pragma unroll
    for (int u = 0; u < 8; ++u) {
        int idx = u * 256 + tid;          // 0..2047
        int tr = idx >> 5, c4 = idx & 31;
        f32x4 t = *reinterpret_cast<const f32x4*>(
            vg + ((t0 + tr) * KH_ + kh) * D_ + c4 * 4);
        bf16_t* dst = &lt[tr * 130 + c4 * 4];
        dst[0] = (bf16_t)t[0]; dst[1] = (bf16_t)t[1];
        dst[2] = (bf16_t)t[2]; dst[3] = (bf16_t)t[3];
    }
    __syncthreads();
    const int nwin = S >> 5;
    #pragma unroll
    for (int u = 0; u < 4; ++u) {
        int idx = u * 256 + tid;          // 0..1023 (2 windows x 512 chunks)
        int wl = idx >> 9;
        int m  = idx & 511;
        int g = m >> 4, r = m & 15, i = r >> 2, cs = r & 3;
        int d = g * 4 + i;
        int c = cs ^ i ^ (g & 3);
        int k0 = wl * 32 + c * 8;         // token within the 64-tile
        bf16x8 w;
        #pragma unroll
        for (int j = 0; j < 8; ++j) w[j] = lt[(k0 + j) * 130 + d];
        long base = ((long)(b * KH_ + kh) * nwin + (s0 >> 5) + wl) * 4096;
        *reinterpret_cast<bf16x8*>(wv + base + m * 8) = w;
    }
}

__global__ __launch_bounds__(256, 3)
void fa_fwd(const float* __restrict__ qg,
            const bf16_t* __restrict__ wk,
            const bf16_t* __restrict__ wv,
            float* __restrict__ og,
            int S, int nqt, int B)
{
    // ---- quad-XCD swizzle + LPT decode
    const int nwg = gridDim.x;
    const int dsp = blockIdx.x;
    int gid;
    if ((nwg & 31) == 0) {
        const int xcd  = dsp & 7;
        const int slot = dsp >> 3;
        gid = 4 * (xcd + 8 * (slot >> 2)) + (slot & 3);
    } else {
        gid = dsp;
    }
    const int hbN  = H_ * B;
    const int rank = gid / hbN;
    const int hb   = gid - rank * hbN;
    const int h    = hb & (H_ - 1);
    const int b    = hb >> 4;
    const int qt   = (nqt - 1) - rank;
    const int kh   = h / (H_ / KH_);

    const int tid  = threadIdx.x;
    const int wid  = tid >> 6;
    const int lane = tid & 63;
    const int l32  = lane & 31;
    const int hi   = lane >> 5;

    __shared__ bf16_t lds_k[2][BN * D_];  // [32][128] bf16 swizzled, 8KB ea
    __shared__ bf16_t lds_v[2][BN * D_];  // [128][32] bf16 2-lvl XOR, 8KB ea

    const int  q0   = qt * BM;
    const long tok0 = (long)b * S;
    const int  qrow = q0 + wid * 32 + l32;

    // ---- Q fragments, pre-scaled by SCALE*log2e (base-2 softmax domain)
    bf16x8 qfrag[8];
    {
        const float* qp = qg + ((tok0 + qrow) * H_ + h) * D_;
        #pragma unroll
        for (int dk = 0; dk < 8; ++dk) {
            f32x4 a = *reinterpret_cast<const f32x4*>(qp + dk * 16 + 8 * hi);
            f32x4 c = *reinterpret_cast<const f32x4*>(qp + dk * 16 + 8 * hi + 4);
            #pragma unroll
            for (int j = 0; j < 4; ++j) {
                qfrag[dk][j]     = (bf16_t)(a[j] * QSC);
                qfrag[dk][j + 4] = (bf16_t)(c[j] * QSC);
            }
        }
    }

    f32x16 oacc[4];
    #pragma unroll
    for (int i = 0; i < 4; ++i)
        #pragma unroll
        for (int e = 0; e < 16; ++e) oacc[i][e] = 0.f;
    float m_i = NEG_INIT, l_i = 0.f;

    const bf16_t* kseq  = wk + (tok0 * KH_ + kh) * D_;
    const bf16_t* vrowb = wv + (long)(b * KH_ + kh) * (S >> 5) * 4096;

    const int nkt = 4 * qt + 4;           // BN=32: tiles up to diagonal

    // issue-early DMA stage of one K/V tile into buffer bufidx
    auto STAGE = [&](int kstage, int bufidx) {
        #pragma unroll
        for (int i = 0; i < 2; ++i) {
            const int slot = i * 256 + tid;        // 0..511
            const int row = slot >> 4, c16 = slot & 15;
            const bf16_t* src = kseq + ((long)(kstage + row) * KH_) * D_
                                + c16 * 8;
            __builtin_amdgcn_global_load_lds(
                (const __attribute__((address_space(1))) unsigned int*)src,
                (__attribute__((address_space(3))) unsigned int*)
                    ((char*)&lds_k[bufidx][0] + slot * 16),
                16, 0, 0);
        }
        const bf16_t* vwin = vrowb + (long)(kstage >> 5) * 4096;
        #pragma unroll
        for (int i = 0; i < 2; ++i) {
            const int m = i * 256 + tid;           // 0..511
            const bf16_t* src = vwin + m * 8;
            __builtin_amdgcn_global_load_lds(
                (const __attribute__((address_space(1))) unsigned int*)src,
                (__attribute__((address_space(3))) unsigned int*)
                    ((char*)&lds_v[bufidx][0] + m * 16),
                16, 0, 0);
        }
    };

    // ---- prologue: stage tile 0; barrier drains vmcnt
    STAGE(0, 0);
    __syncthreads();

    int cur = 0;
    for (int kt = 0; kt < nkt; ++kt) {
        const int kst = kt * BN;

        // ---- 2-phase: issue next tile's DMA BEFORE computing this one
        if (kt + 1 < nkt) STAGE(kst + BN, cur ^ 1);

        // fully-masked wave on trailing diagonal tiles: skip compute
        if (kst <= q0 + wid * 32 + 31) {
            const char* kbuf = (const char*)&lds_k[cur][0];
            const char* vbuf = (const char*)&lds_v[cur][0];

            // ---- S^T = K Q^T (32x32x16), swizzled K reads (2-way = free)
            f32x16 s;
            {
                f32x16 acc;
                #pragma unroll
                for (int e = 0; e < 16; ++e) acc[e] = 0.f;
                __builtin_amdgcn_s_setprio(1);
                #pragma unroll
                for (int dk = 0; dk < 8; ++dk) {
                    const int byte = l32 * 256
                                   + ((dk * 32 + 16 * hi) ^ ((l32 & 15) << 4));
                    bf16x8 kf = *reinterpret_cast<const bf16x8*>(kbuf + byte);
                    acc = __builtin_amdgcn_mfma_f32_32x32x16_bf16(kf, qfrag[dk], acc, 0, 0, 0);
                }
                __builtin_amdgcn_s_setprio(0);
                s = acc;   // key = kst + (r&3) + 8*(r>>2) + 4*hi, q = l32
            }

            // ---- mask (Q pre-scaled: no scale op)
            if (kst + BN - 1 > q0 + wid * 32) {
                #pragma unroll
                for (int r = 0; r < 16; ++r) {
                    const int key = kst + (r & 3) + 8 * (r >> 2) + 4 * hi;
                    if (key > qrow) s[r] = NEG_MASK;
                }
            }

            // ---- online softmax, base-2 (16 in-reg + 1 shfl)
            float mx = s[0];
            #pragma unroll
            for (int r = 1; r < 16; ++r) mx = fmaxf(mx, s[r]);
            mx = fmaxf(mx, __shfl_xor(mx, 32));

            float mn_use = m_i;
            if (!__all(mx - m_i <= DEFER_THR2)) {    // T13 defer-max
                const float mn    = fmaxf(m_i, mx);
                const float alpha = exp2fast(m_i - mn);
                l_i *= alpha;
                m_i = mn;
                mn_use = mn;
                #pragma unroll
                for (int dt = 0; dt < 4; ++dt)
                    #pragma unroll
                    for (int e = 0; e < 16; ++e)
                        oacc[dt][e] *= alpha;
            }

            // ---- exp2 + row-sum + pack (s dies into Pu)
            // Pu[i] = keys 8*(i>>1) + 4*hi + 2*(i&1) + {0,1}
            unsigned Pu[8];
            float rs = 0.f;
            #pragma unroll
            for (int i = 0; i < 8; ++i) {
                float p0 = exp2fast(s[2 * i]     - mn_use);
                float p1 = exp2fast(s[2 * i + 1] - mn_use);
                rs += p0 + p1;
                bf16x2 t;
                t[0] = (bf16_t)p0;
                t[1] = (bf16_t)p1;
                Pu[i] = __builtin_bit_cast(unsigned, t);
            }
            rs += __shfl_xor(rs, 32);
            l_i += rs;

            // ---- O^T += V^T P^T, lazy pf build; 2-level XOR V reads
            __builtin_amdgcn_s_setprio(1);
            #pragma unroll
            for (int ks = 0; ks < 2; ++ks) {
                const int b4 = 4 * ks;
                unsigned v0 = hi ? Pu[b4 + 0] : Pu[b4 + 2];
                unsigned v1 = hi ? Pu[b4 + 1] : Pu[b4 + 3];
                unsigned x0 = (unsigned)__shfl_xor((int)v0, 32);
                unsigned x1 = (unsigned)__shfl_xor((int)v1, 32);
                u32x4 pu;
                pu[0] = hi ? x0 : Pu[b4 + 0];
                pu[1] = hi ? x1 : Pu[b4 + 1];
                pu[2] = hi ? Pu[b4 + 2] : x0;
                pu[3] = hi ? Pu[b4 + 3] : x1;
                bf16x8 pf = __builtin_bit_cast(bf16x8, pu);
                const int c = ks * 2 + hi;            // 16B key-chunk 0..3
                #pragma unroll
                for (int dt = 0; dt < 4; ++dt) {
                    const int d = dt * 32 + l32;
                    const int g = d >> 2, ii = d & 3;
                    const int byte = g * 256 + ii * 64
                                   + ((c ^ ii ^ (g & 3)) << 4);
                    bf16x8 vf = *reinterpret_cast<const bf16x8*>(vbuf + byte);
                    oacc[dt] = __builtin_amdgcn_mfma_f32_32x32x16_bf16(vf, pf, oacc[dt], 0, 0, 0);
                }
            }
            __builtin_amdgcn_s_setprio(0);
        }

        // one barrier per tile: drains the prefetch (issued a compute-phase
        // ago) and fences this tile's LDS reads before the next overwrite
        __syncthreads();
        cur ^= 1;
    }

    // ---- epilogue
    const float inv = 1.0f / l_i;
    float* op = og + ((tok0 + qrow) * H_ + h) * D_;
    #pragma unroll
    for (int dt = 0; dt < 4; ++dt)
        #pragma unroll
        for (int g = 0; g < 4; ++g) {
            f32x4 o;
            #pragma unroll
            for (int r = 0; r < 4; ++r) o[r] = oacc[dt][4 * g + r] * inv;
            *reinterpret_cast<f32x4*>(op + dt * 32 + 8 * g + 4 * hi) = o;
        }
}

extern "C" void kernel_launch(void* const* d_in, const int* in_sizes, int n_in,
                              void* d_out, int out_size, void* d_ws, size_t ws_size,
                              hipStream_t stream) {
    const float* q = (const float*)d_in[0];
    const float* k = (const float*)d_in[1];
    const float* v = (const float*)d_in[2];
    float* out = (float*)d_out;

    const int B = in_sizes[3] - 1;
    const int T = in_sizes[0] / (H_ * D_);
    const int S = T / B;
    const int nqt = S / BM;

    bf16_t* wk = (bf16_t*)d_ws;                       // [T*KH][128] bf16
    bf16_t* wv = wk + (size_t)T * KH_ * D_;           // [B*KH][S/32][4096]

    const int nchunks = T * KH_ * 16;                 // 16B chunks in K
    prep_k<<<(nchunks + 255) / 256, 256, 0, stream>>>(k, wk, nchunks);
    prep_v<<<(T / 64) * KH_, 256, 0, stream>>>(v, wv, S);

    dim3 grid(nqt * H_ * B);
    fa_fwd<<<grid, 256, 0, stream>>>(q, wk, wv, out, S, nqt, B);
}